// Round 14
// baseline (828.888 us; speedup 1.0000x reference)
//
#include <hip/hip_runtime.h>
#include <hip/hip_bf16.h>
#include <math.h>

// CGConv: N=100000 atoms, M=12 nbrs, F=64 atom-feat, B=41 bond-feat
// gated = [self | nbr | bond] @ W + b ; BN1 over N*M rows ;
// summed = sum_j sigmoid(filter)*softplus(core) ; BN2 over N rows ;
// out = softplus(atom + summed_bn)
//
// R14: BARRIER-FREE pair GEMM. R13 disproved the occupancy theory (61% occ,
// no spill, SLOWER) -> the per-group __syncthreads pair is the correlated
// stall (all waves drain vmcnt together). A-tile has zero cross-wave reuse,
// so A-fragments are loaded straight from global into VGPRs (nbr = uint4
// from atomBf in exact fragment layout; bond = 8 scalar f32 + cvt_pk).
// W fragments move to LDS (32KB, loaded once, conflict-free reads) so ONE
// wave owns a whole group and all 8 n-tiles. One barrier at kernel start,
// none in the loop; 8192 independent wave-streams hide latency (m114).
// launch_bounds(256,3): demand ~115 regs incl AGPR < ~170 cap (R12 lesson:
// cap < demand spills catastrophically; VGPR_Count excludes AGPRs).
// BN1 two-pass forced (sumsq cross-term per-pair); bias b cancels in BN1.

#define NATOMS  100000
#define MNBR    12
#define FDIM    64
#define BDIM    41
#define C2F     128
#define EPSBN   1e-5f
#define NBLK    2048              // k_gemm/k_apply grid
#define NWAVES  (NBLK*4)          // stats partial slots (1 per wave)
#define GROUPS  (NATOMS/4)        // 25000 groups of 4 atoms = 48 pairs
#define PR      72                // proj A-tile row stride (shorts)

typedef __attribute__((ext_vector_type(8))) short  short8;   // bf16 x8 frag
typedef __attribute__((ext_vector_type(4))) float  f32x4;    // C/D frag

__device__ __forceinline__ float softplusf(float x) {
    return fmaxf(x, 0.f) + __logf(1.f + __expf(-fabsf(x)));
}
__device__ __forceinline__ float sigmoidf(float x) {
    return 1.f / (1.f + __expf(-x));
}
__device__ __forceinline__ unsigned short f2bf(float f) {
    unsigned int x = __builtin_bit_cast(unsigned int, f);
    unsigned int r = (x + 0x7fff + ((x >> 16) & 1)) >> 16;  // RNE
    return (unsigned short)r;
}
__device__ __forceinline__ unsigned int pkbf(float a, float b) {
    unsigned short lo = __builtin_bit_cast(unsigned short, __float2bfloat16(a));
    unsigned short hi = __builtin_bit_cast(unsigned short, __float2bfloat16(b));
    return (unsigned)lo | ((unsigned)hi << 16);
}
__device__ __forceinline__ float bflo(unsigned int u) {
    return __builtin_bit_cast(float, u << 16);
}
__device__ __forceinline__ float bfhi(unsigned int u) {
    return __builtin_bit_cast(float, u & 0xffff0000u);
}
__device__ __forceinline__ float bf2f(unsigned short u) {
    return __builtin_bit_cast(float, ((unsigned int)u) << 16);
}

// ---------------- kernel 0: prepack W fragments ----------------
// Wsn: self rows,  [n<8][ks<2][lane][e], k = ks*32+(lane>>4)*8+e, col=n*16+(lane&15)
// Wpk: nbr+bond rows, [n<8][ks<4][lane][e]; k<105 -> W[64+k][col] else 0
__global__ __launch_bounds__(256) void k_pack(
    const float* __restrict__ W,
    unsigned short* __restrict__ Wsn, unsigned short* __restrict__ Wpk)
{
    const int t0 = blockIdx.x*256 + threadIdx.x;
    for (int idx = t0; idx < 8*2*64*8; idx += gridDim.x*256) {
        int e = idx & 7, lane = (idx >> 3) & 63, ks = (idx >> 9) & 1, n = idx >> 10;
        int k   = ks*32 + (lane >> 4)*8 + e;
        int col = n*16 + (lane & 15);
        Wsn[idx] = f2bf(W[k*C2F + col]);
    }
    for (int idx = t0; idx < 8*4*64*8; idx += gridDim.x*256) {
        int e = idx & 7, lane = (idx >> 3) & 63, ks = (idx >> 9) & 3, n = idx >> 11;
        int k   = ks*32 + (lane >> 4)*8 + e;
        int col = n*16 + (lane & 15);
        float v = (k < 105) ? W[(64 + k)*C2F + col] : 0.f;
        Wpk[idx] = f2bf(v);
    }
}

// ---------------- kernel 1: Pself (MFMA) + atomBf pack ----------------
__global__ __launch_bounds__(256, 4) void k_proj(
    const float* __restrict__ atomF, const unsigned short* __restrict__ Wsn,
    unsigned short* __restrict__ PselfBf, unsigned short* __restrict__ atomBf)
{
    __shared__ __align__(16) unsigned short A[64*PR];
    const int tid = threadIdx.x, w = tid >> 6, lane = tid & 63;
    const int g = lane >> 4, x = lane & 15;
    short8 B0[2], B1[2];
    #pragma unroll
    for (int ks = 0; ks < 2; ++ks) {
        B0[ks] = *(const short8*)(Wsn + ((w*2 + ks)*64 + lane)*8);
        B1[ks] = *(const short8*)(Wsn + (((w+4)*2 + ks)*64 + lane)*8);
    }
    for (int a0 = blockIdx.x*64; a0 < NATOMS; a0 += gridDim.x*64) {
        __syncthreads();
        #pragma unroll
        for (int it = 0; it < 4; ++it) {
            int idx = it*256 + tid;
            int p = idx >> 4, c = idx & 15;
            int i = a0 + p;
            float4 v = make_float4(0.f, 0.f, 0.f, 0.f);
            if (i < NATOMS) v = *(const float4*)(atomF + (size_t)i*FDIM + 4*c);
            uint2 u; u.x = pkbf(v.x, v.y); u.y = pkbf(v.z, v.w);
            *(uint2*)(A + p*PR + 4*c) = u;
            if (i < NATOMS) *(uint2*)(atomBf + (size_t)i*FDIM + 4*c) = u;
        }
        __syncthreads();
        f32x4 z = {0.f, 0.f, 0.f, 0.f};
        f32x4 acc[4][2];
        #pragma unroll
        for (int m = 0; m < 4; ++m) { acc[m][0] = z; acc[m][1] = z; }
        #pragma unroll
        for (int ks = 0; ks < 2; ++ks) {
            #pragma unroll
            for (int m = 0; m < 4; ++m) {
                short8 a = *(const short8*)(A + (m*16 + x)*PR + ks*32 + g*8);
                acc[m][0] = __builtin_amdgcn_mfma_f32_16x16x32_bf16(a, B0[ks], acc[m][0], 0, 0, 0);
                acc[m][1] = __builtin_amdgcn_mfma_f32_16x16x32_bf16(a, B1[ks], acc[m][1], 0, 0, 0);
            }
        }
        #pragma unroll
        for (int m = 0; m < 4; ++m) {
            int i = a0 + m*16 + g*4;
            #pragma unroll
            for (int rg = 0; rg < 4; ++rg) {
                if (i + rg < NATOMS) {
                    PselfBf[(size_t)(i+rg)*C2F + w*16 + x]     = f2bf(acc[m][0][rg]);
                    PselfBf[(size_t)(i+rg)*C2F + (w+4)*16 + x] = f2bf(acc[m][1][rg]);
                }
            }
        }
    }
}

// ---------------- kernel 2: barrier-free pair GEMM ----------------
// One wave per group-stream. A-fragments loaded DIRECT from global:
//   nbr   (ks 0,1): uint4 at atomBf + r*64 + ks*32 + g*8  (exact frag layout)
//   bond  (ks 2)  : 8 scalar f32 at bond_row + g*8, cvt_pk packed
//   bond  (ks 3)  : g=0: elems 32..39; g=1: elem 40; g>=2: zero
// B-fragments (Wpk, 32KB) in LDS, loaded once (single barrier at start).
// Per group: for n in 0..8 { 4 ds_read B; for m in 0..3 { 4 MFMA; epilogue } }.
// gated layout (uint2 planes): flat = ((grp*3 + m)*8 + n)*64 + lane.
__global__ __launch_bounds__(256, 3) void k_gemm(
    const int* __restrict__ nbr, const unsigned short* __restrict__ atomBf,
    const float* __restrict__ bond, const unsigned short* __restrict__ Wpk,
    const unsigned short* __restrict__ PselfBf,
    uint2* __restrict__ gated, float* __restrict__ partial1)
{
    __shared__ __align__(16) unsigned short Wl[16384];    // 32KB B-frags
    const int tid = threadIdx.x, w = tid >> 6, lane = tid & 63;
    const int g = lane >> 4, x = lane & 15;
    for (int i = tid; i < 8192; i += 256)
        ((unsigned int*)Wl)[i] = ((const unsigned int*)Wpk)[i];
    __syncthreads();                                      // the ONLY barrier

    float s[8] = {0,0,0,0,0,0,0,0};
    float q[8] = {0,0,0,0,0,0,0,0};
    const int wid = blockIdx.x*4 + w;
    const int NW  = gridDim.x*4;

    for (int grp = wid; grp < GROUPS; grp += NW) {
        const int base4 = grp*4;
        uint4 A[3][4];
        int   ia[3];
        #pragma unroll
        for (int m = 0; m < 3; ++m) {
            const int p = m*16 + x;
            const int r = nbr[grp*48 + p];
            const unsigned short* ab = atomBf + ((size_t)r << 6);
            A[m][0] = *(const uint4*)(ab +      g*8);
            A[m][1] = *(const uint4*)(ab + 32 + g*8);
            const float* bp = bond + ((size_t)grp*48 + p)*BDIM;
            {
                float b0 = bp[g*8+0], b1 = bp[g*8+1], b2 = bp[g*8+2], b3 = bp[g*8+3];
                float b4 = bp[g*8+4], b5 = bp[g*8+5], b6 = bp[g*8+6], b7 = bp[g*8+7];
                A[m][2].x = pkbf(b0,b1); A[m][2].y = pkbf(b2,b3);
                A[m][2].z = pkbf(b4,b5); A[m][2].w = pkbf(b6,b7);
            }
            uint4 a3 = {0u,0u,0u,0u};
            if (g == 0) {
                float c0 = bp[32], c1 = bp[33], c2 = bp[34], c3 = bp[35];
                float c4 = bp[36], c5 = bp[37], c6 = bp[38], c7 = bp[39];
                a3.x = pkbf(c0,c1); a3.y = pkbf(c2,c3);
                a3.z = pkbf(c4,c5); a3.w = pkbf(c6,c7);
            } else if (g == 1) {
                a3.x = pkbf(bp[40], 0.f);
            }
            A[m][3] = a3;
            ia[m] = base4 + (m*16 + g*4)/12;              // uniform over rg (proven)
        }
        #pragma unroll
        for (int n = 0; n < 8; ++n) {
            short8 B0 = *(const short8*)(Wl + ((n*4 + 0)*64 + lane)*8);
            short8 B1 = *(const short8*)(Wl + ((n*4 + 1)*64 + lane)*8);
            short8 B2 = *(const short8*)(Wl + ((n*4 + 2)*64 + lane)*8);
            short8 B3 = *(const short8*)(Wl + ((n*4 + 3)*64 + lane)*8);
            const int ch = n*16 + x;
            #pragma unroll
            for (int m = 0; m < 3; ++m) {
                f32x4 acc = {0.f, 0.f, 0.f, 0.f};
                acc = __builtin_amdgcn_mfma_f32_16x16x32_bf16(
                          __builtin_bit_cast(short8, A[m][0]), B0, acc, 0, 0, 0);
                acc = __builtin_amdgcn_mfma_f32_16x16x32_bf16(
                          __builtin_bit_cast(short8, A[m][1]), B1, acc, 0, 0, 0);
                acc = __builtin_amdgcn_mfma_f32_16x16x32_bf16(
                          __builtin_bit_cast(short8, A[m][2]), B2, acc, 0, 0, 0);
                acc = __builtin_amdgcn_mfma_f32_16x16x32_bf16(
                          __builtin_bit_cast(short8, A[m][3]), B3, acc, 0, 0, 0);
                float ps = bf2f(PselfBf[(size_t)ia[m]*C2F + ch]);
                float v0 = acc[0] + ps, v1 = acc[1] + ps;
                float v2 = acc[2] + ps, v3 = acc[3] + ps;
                s[n] += (v0 + v1) + (v2 + v3);
                q[n] = fmaf(v0, v0, q[n]); q[n] = fmaf(v1, v1, q[n]);
                q[n] = fmaf(v2, v2, q[n]); q[n] = fmaf(v3, v3, q[n]);
                uint2 pk;
                pk.x = pkbf(v0, v1); pk.y = pkbf(v2, v3);
                gated[(((size_t)grp*3 + m)*8 + n)*64 + lane] = pk;
            }
        }
    }
    #pragma unroll
    for (int n = 0; n < 8; ++n) {
        s[n] += __shfl_xor(s[n], 16); s[n] += __shfl_xor(s[n], 32);
        q[n] += __shfl_xor(q[n], 16); q[n] += __shfl_xor(q[n], 32);
    }
    if (g == 0) {
        float* pb = partial1 + (size_t)wid*256;           // {sum[128], sumsq[128]}
        #pragma unroll
        for (int n = 0; n < 8; ++n) {
            pb[n*16 + x]       = s[n];
            pb[128 + n*16 + x] = q[n];
        }
    }
}

// ---------------- kernel: partial reduce (rows = 128*per) -> 128 ----------------
__global__ __launch_bounds__(256) void k_red(
    const float* __restrict__ in, float* __restrict__ outp, int width, int per)
{
    const int b = blockIdx.x;
    for (int c = threadIdx.x; c < width; c += 256) {
        float s = 0.f;
        for (int k = 0; k < per; ++k) s += in[(size_t)(b*per + k)*width + c];
        outp[(size_t)b*width + c] = s;
    }
}

// ---------------- kernel 3: finalize BN1 params ----------------
__global__ __launch_bounds__(1024) void k_bn1_finalize(
    const float* __restrict__ red1, const float* __restrict__ scale,
    const float* __restrict__ offset, float* __restrict__ prm1)
{
    __shared__ float redS[1024], redQ[1024];
    const int tid = threadIdx.x, c = tid & 127, h = tid >> 7;   // 8 slices
    float S = 0.f, Q = 0.f;
    for (int blk = h; blk < 128; blk += 8) {
        S += red1[blk*256 + c];
        Q += red1[blk*256 + 128 + c];
    }
    redS[tid] = S; redQ[tid] = Q;
    __syncthreads();
    if (tid < 128) {
        float Sa = 0.f, Qa = 0.f;
        #pragma unroll
        for (int hh = 0; hh < 8; ++hh) { Sa += redS[hh*128 + c]; Qa += redQ[hh*128 + c]; }
        const float invn = 1.f / (float)(NATOMS * MNBR);
        float mean = Sa * invn;
        float var  = Qa * invn - mean*mean;
        float inv  = scale[c] * rsqrtf(var + EPSBN);
        prm1[c]       = inv;
        prm1[128 + c] = offset[c] - mean*inv;       // folded offset
    }
}

// ---------------- kernel 4: apply pass (stream gated, gate, nbr-sum) ----------------
// Thread (w, lane): filter ch0 = w*16+x from n-tile w, core ch0+64 from
// n-tile w+4 -- two coalesced uint2 streams.
__global__ __launch_bounds__(256, 8) void k_apply(
    const uint2* __restrict__ gated, const float* __restrict__ prm1,
    float* __restrict__ summed, float* __restrict__ partial2)
{
    __shared__ float Y[12*66];
    __shared__ float red[256];
    const int tid = threadIdx.x, w = tid >> 6, lane = tid & 63;
    const int g = lane >> 4, x = lane & 15;
    const int ch0 = w*16 + x;
    const float iv0 = prm1[ch0],      of0 = prm1[C2F + ch0];
    const float iv1 = prm1[64 + ch0], of1 = prm1[C2F + 64 + ch0];
    float s2 = 0.f, q2 = 0.f;

    for (int grp = blockIdx.x; grp < GROUPS; grp += gridDim.x) {
        __syncthreads();
        #pragma unroll
        for (int m = 0; m < 3; ++m) {
            const uint2* gb = gated + ((size_t)grp*3 + m)*8*64;
            uint2 uF = gb[w*64 + lane];            // filter plane (n-tile w)
            uint2 uC = gb[(w+4)*64 + lane];        // core plane (n-tile w+4)
            float y00 = bflo(uF.x)*iv0 + of0, y01 = bfhi(uF.x)*iv0 + of0;
            float y02 = bflo(uF.y)*iv0 + of0, y03 = bfhi(uF.y)*iv0 + of0;
            float y10 = bflo(uC.x)*iv1 + of1, y11 = bfhi(uC.x)*iv1 + of1;
            float y12 = bflo(uC.y)*iv1 + of1, y13 = bfhi(uC.y)*iv1 + of1;
            float sY = sigmoidf(y00)*softplusf(y10) + sigmoidf(y01)*softplusf(y11)
                     + sigmoidf(y02)*softplusf(y12) + sigmoidf(y03)*softplusf(y13);
            Y[(m*4 + g)*66 + ch0] = sY;
        }
        __syncthreads();
        float sv = Y[(3*w)*66 + lane] + Y[(3*w + 1)*66 + lane] + Y[(3*w + 2)*66 + lane];
        summed[(size_t)(grp*4 + w)*FDIM + lane] = sv;
        s2 += sv; q2 = fmaf(sv, sv, q2);
    }
    red[tid] = s2; __syncthreads();
    if (tid < 64) partial2[blockIdx.x*128 + tid]
        = red[tid] + red[tid+64] + red[tid+128] + red[tid+192];
    __syncthreads();
    red[tid] = q2; __syncthreads();
    if (tid < 64) partial2[blockIdx.x*128 + 64 + tid]
        = red[tid] + red[tid+64] + red[tid+128] + red[tid+192];
}

// ---------------- kernel 5: finalize BN2 params ----------------
__global__ __launch_bounds__(1024) void k_bn2_finalize(
    const float* __restrict__ red2, const float* __restrict__ scale,
    const float* __restrict__ offset, float* __restrict__ prm2)
{
    __shared__ float redS[1024], redQ[1024];
    const int tid = threadIdx.x, f = tid & 63, h = tid >> 6;    // 16 slices
    float S = 0.f, Q = 0.f;
    for (int blk = h; blk < 128; blk += 16) {
        S += red2[blk*128 + f];
        Q += red2[blk*128 + 64 + f];
    }
    redS[tid] = S; redQ[tid] = Q;
    __syncthreads();
    if (tid < 64) {
        float Sa = 0.f, Qa = 0.f;
        #pragma unroll
        for (int hh = 0; hh < 16; ++hh) { Sa += redS[hh*64 + f]; Qa += redQ[hh*64 + f]; }
        const float invn = 1.f / (float)NATOMS;
        float mean = Sa * invn;
        float var  = Qa * invn - mean*mean;
        float inv  = scale[f] * rsqrtf(var + EPSBN);
        prm2[f]      = inv;
        prm2[64 + f] = offset[f] - mean*inv;
    }
}

// ---------------- kernel 6: residual + softplus ----------------
__global__ __launch_bounds__(256) void k_final(
    const float* __restrict__ atomF, const float* __restrict__ summed,
    const float* __restrict__ prm2, float* __restrict__ out)
{
    __shared__ float iv[64], of[64];
    if (threadIdx.x < 64) {
        iv[threadIdx.x] = prm2[threadIdx.x];
        of[threadIdx.x] = prm2[64 + threadIdx.x];
    }
    __syncthreads();
    const int total4 = NATOMS*FDIM/4;
    for (int t = blockIdx.x*blockDim.x + threadIdx.x; t < total4;
         t += gridDim.x*blockDim.x) {
        float4 a = ((const float4*)atomF)[t];
        float4 s = ((const float4*)summed)[t];
        int fb = (t*4) & 63;
        float4 r;
        r.x = softplusf(a.x + s.x*iv[fb]   + of[fb]);
        r.y = softplusf(a.y + s.y*iv[fb+1] + of[fb+1]);
        r.z = softplusf(a.z + s.z*iv[fb+2] + of[fb+2]);
        r.w = softplusf(a.w + s.w*iv[fb+3] + of[fb+3]);
        ((float4*)out)[t] = r;
    }
}

extern "C" void kernel_launch(void* const* d_in, const int* in_sizes, int n_in,
                              void* d_out, int out_size, void* d_ws, size_t ws_size,
                              hipStream_t stream)
{
    const int*   nbr   = (const int*)  d_in[0];
    const float* atomF = (const float*)d_in[1];
    const float* bond  = (const float*)d_in[2];
    const float* W     = (const float*)d_in[3];
    // d_in[4] = b: cancels through BN1 (shift invariance) -> unused
    const float* s1    = (const float*)d_in[5];
    const float* o1    = (const float*)d_in[6];
    const float* s2    = (const float*)d_in[7];
    const float* o2    = (const float*)d_in[8];
    float* out = (float*)d_out;

    // ws layout (~385 MB total)
    uint2* gated        = (uint2*)d_ws;                          // GROUPS*3*8*64*8B = 307.2MB
    unsigned short* PselfBf = (unsigned short*)(gated + (size_t)GROUPS*3*8*64);  // N*128 bf16
    unsigned short* atomBf  = PselfBf + (size_t)NATOMS*C2F;      // N*64 bf16
    float* summed   = (float*)(atomBf + (size_t)NATOMS*FDIM);    // N*64 f32
    float* partial1 = summed   + (size_t)NATOMS*FDIM;            // NWAVES*256 (8MB)
    float* partial2 = partial1 + (size_t)NWAVES*256;             // 2048*128
    float* red1     = partial2 + (size_t)NBLK*128;               // 128*256
    float* red2     = red1     + 128*256;                        // 128*128
    float* prm1     = red2     + 128*128;                        // 256
    float* prm2     = prm1     + 256;                            // 128
    unsigned short* Wsn = (unsigned short*)(prm2 + 128);         // 8192 shorts
    unsigned short* Wpk = Wsn + 8192;                            // 16384 shorts

    hipLaunchKernelGGL(k_pack,         dim3(64),   dim3(256),  0, stream, W, Wsn, Wpk);
    hipLaunchKernelGGL(k_proj,         dim3(782),  dim3(256),  0, stream,
                       atomF, Wsn, PselfBf, atomBf);
    hipLaunchKernelGGL(k_gemm,         dim3(NBLK), dim3(256),  0, stream,
                       nbr, atomBf, bond, Wpk, PselfBf, gated, partial1);
    hipLaunchKernelGGL(k_red,          dim3(128),  dim3(256),  0, stream,
                       partial1, red1, 256, NWAVES/128);
    hipLaunchKernelGGL(k_bn1_finalize, dim3(1),    dim3(1024), 0, stream, red1, s1, o1, prm1);
    hipLaunchKernelGGL(k_apply,        dim3(NBLK), dim3(256),  0, stream,
                       gated, prm1, summed, partial2);
    hipLaunchKernelGGL(k_red,          dim3(128),  dim3(256),  0, stream,
                       partial2, red2, 128, NBLK/128);
    hipLaunchKernelGGL(k_bn2_finalize, dim3(1),    dim3(1024), 0, stream, red2, s2, o2, prm2);
    hipLaunchKernelGGL(k_final,        dim3(2048), dim3(256),  0, stream, atomF, summed, prm2, out);
}

// Round 15
// 578.576 us; speedup vs baseline: 1.4326x; 1.4326x over previous
//
#include <hip/hip_runtime.h>
#include <hip/hip_bf16.h>
#include <math.h>

// CGConv: N=100000 atoms, M=12 nbrs, F=64 atom-feat, B=41 bond-feat
// gated = [self | nbr | bond] @ W + b ; BN1 over N*M rows ;
// summed = sum_j sigmoid(filter)*softplus(core) ; BN2 over N rows ;
// out = softplus(atom + summed_bn)
//
// R15 = R11 (best, 372us) with 2-group barrier epochs in k_gemm.
// R13 (more waves, same barriers: slower) + R14 (no barriers, direct
// gather: 5x fetch) bracket the diagnosis: keep R11's coalesced staged
// gather (fetch was byte-ideal 242MB), halve the barrier drains, and
// double the prefetch window. 4 LDS buffers (52KB), each epoch:
// barrier -> GATHER groups t+2,t+3 (indices resident, 2-deep pipeline)
// -> 48 MFMA + 2 epilogues (covers gather latency) -> WRITEA both.
// launch_bounds(256,3): staging regs +36 over R11 which sat at exactly
// 64 VGPR + 64 AGPR = 128 (gfx950 unified file) -> cap 170 avoids the
// R2/R10/R12 spill disease; LDS limits to 3 blocks/CU regardless.
// BN1 two-pass forced (sumsq cross-term per-pair); bias b cancels in BN1.

#define NATOMS  100000
#define MNBR    12
#define FDIM    64
#define BDIM    41
#define C2F     128
#define EPSBN   1e-5f
#define NBLK    2048              // pair-kernel grid (= #partial slots)
#define GROUPS  (NATOMS/4)        // 25000 groups of 4 atoms = 48 pairs
#define AR      136               // pair A-tile row stride (shorts)
#define PR      72                // proj A-tile row stride (shorts)

typedef __attribute__((ext_vector_type(8))) short  short8;   // bf16 x8 frag
typedef __attribute__((ext_vector_type(4))) float  f32x4;    // C/D frag

__device__ __forceinline__ float softplusf(float x) {
    return fmaxf(x, 0.f) + __logf(1.f + __expf(-fabsf(x)));
}
__device__ __forceinline__ float sigmoidf(float x) {
    return 1.f / (1.f + __expf(-x));
}
__device__ __forceinline__ unsigned short f2bf(float f) {
    unsigned int x = __builtin_bit_cast(unsigned int, f);
    unsigned int r = (x + 0x7fff + ((x >> 16) & 1)) >> 16;  // RNE
    return (unsigned short)r;
}
__device__ __forceinline__ unsigned int pkbf(float a, float b) {
    unsigned short lo = __builtin_bit_cast(unsigned short, __float2bfloat16(a));
    unsigned short hi = __builtin_bit_cast(unsigned short, __float2bfloat16(b));
    return (unsigned)lo | ((unsigned)hi << 16);
}
__device__ __forceinline__ float bflo(unsigned int u) {
    return __builtin_bit_cast(float, u << 16);
}
__device__ __forceinline__ float bfhi(unsigned int u) {
    return __builtin_bit_cast(float, u & 0xffff0000u);
}
__device__ __forceinline__ float bf2f(unsigned short u) {
    return __builtin_bit_cast(float, ((unsigned int)u) << 16);
}

// ---------------- kernel 0: prepack W fragments ----------------
// Wsn: self rows,  [n<8][ks<2][lane][e], k = ks*32+(lane>>4)*8+e, col=n*16+(lane&15)
// Wpk: nbr+bond rows, [n<8][ks<4][lane][e]; k<105 -> W[64+k][col] else 0
__global__ __launch_bounds__(256) void k_pack(
    const float* __restrict__ W,
    unsigned short* __restrict__ Wsn, unsigned short* __restrict__ Wpk)
{
    const int t0 = blockIdx.x*256 + threadIdx.x;
    for (int idx = t0; idx < 8*2*64*8; idx += gridDim.x*256) {
        int e = idx & 7, lane = (idx >> 3) & 63, ks = (idx >> 9) & 1, n = idx >> 10;
        int k   = ks*32 + (lane >> 4)*8 + e;
        int col = n*16 + (lane & 15);
        Wsn[idx] = f2bf(W[k*C2F + col]);
    }
    for (int idx = t0; idx < 8*4*64*8; idx += gridDim.x*256) {
        int e = idx & 7, lane = (idx >> 3) & 63, ks = (idx >> 9) & 3, n = idx >> 11;
        int k   = ks*32 + (lane >> 4)*8 + e;
        int col = n*16 + (lane & 15);
        float v = (k < 105) ? W[(64 + k)*C2F + col] : 0.f;
        Wpk[idx] = f2bf(v);
    }
}

// ---------------- kernel 1: Pself (MFMA) + atomBf pack ----------------
__global__ __launch_bounds__(256, 4) void k_proj(
    const float* __restrict__ atomF, const unsigned short* __restrict__ Wsn,
    unsigned short* __restrict__ PselfBf, unsigned short* __restrict__ atomBf)
{
    __shared__ __align__(16) unsigned short A[64*PR];
    const int tid = threadIdx.x, w = tid >> 6, lane = tid & 63;
    const int g = lane >> 4, x = lane & 15;
    short8 B0[2], B1[2];
    #pragma unroll
    for (int ks = 0; ks < 2; ++ks) {
        B0[ks] = *(const short8*)(Wsn + ((w*2 + ks)*64 + lane)*8);
        B1[ks] = *(const short8*)(Wsn + (((w+4)*2 + ks)*64 + lane)*8);
    }
    for (int a0 = blockIdx.x*64; a0 < NATOMS; a0 += gridDim.x*64) {
        __syncthreads();
        #pragma unroll
        for (int it = 0; it < 4; ++it) {
            int idx = it*256 + tid;
            int p = idx >> 4, c = idx & 15;
            int i = a0 + p;
            float4 v = make_float4(0.f, 0.f, 0.f, 0.f);
            if (i < NATOMS) v = *(const float4*)(atomF + (size_t)i*FDIM + 4*c);
            uint2 u; u.x = pkbf(v.x, v.y); u.y = pkbf(v.z, v.w);
            *(uint2*)(A + p*PR + 4*c) = u;
            if (i < NATOMS) *(uint2*)(atomBf + (size_t)i*FDIM + 4*c) = u;
        }
        __syncthreads();
        f32x4 z = {0.f, 0.f, 0.f, 0.f};
        f32x4 acc[4][2];
        #pragma unroll
        for (int m = 0; m < 4; ++m) { acc[m][0] = z; acc[m][1] = z; }
        #pragma unroll
        for (int ks = 0; ks < 2; ++ks) {
            #pragma unroll
            for (int m = 0; m < 4; ++m) {
                short8 a = *(const short8*)(A + (m*16 + x)*PR + ks*32 + g*8);
                acc[m][0] = __builtin_amdgcn_mfma_f32_16x16x32_bf16(a, B0[ks], acc[m][0], 0, 0, 0);
                acc[m][1] = __builtin_amdgcn_mfma_f32_16x16x32_bf16(a, B1[ks], acc[m][1], 0, 0, 0);
            }
        }
        #pragma unroll
        for (int m = 0; m < 4; ++m) {
            int i = a0 + m*16 + g*4;
            #pragma unroll
            for (int rg = 0; rg < 4; ++rg) {
                if (i + rg < NATOMS) {
                    PselfBf[(size_t)(i+rg)*C2F + w*16 + x]     = f2bf(acc[m][0][rg]);
                    PselfBf[(size_t)(i+rg)*C2F + (w+4)*16 + x] = f2bf(acc[m][1][rg]);
                }
            }
        }
    }
}

// ---------------- kernel 2: pair GEMM + BN1 stats + gated store ----------------
// A rows = [nbr(64) | bond(41) | pad] bf16, K=128 (4 ksteps), M=48 pairs.
// 2-group epochs: 4 LDS buffers; per barrier, GATHER two future groups
// (indices resident via 2-deep rN/rM pipeline), 48 MFMA + 2 epilogues,
// then WRITEA both. Slot map: idx=it*256+tid, p=idx>>5, c=idx&31.
// gated layout: uint4 index = ((grp*4 + w)*3 + m)*64 + lane.
__global__ __launch_bounds__(256, 3) void k_gemm(
    const int* __restrict__ nbr, const unsigned short* __restrict__ atomBf,
    const float* __restrict__ bond, const unsigned short* __restrict__ Wpk,
    const unsigned short* __restrict__ PselfBf,
    uint4* __restrict__ gated, float* __restrict__ partial1)
{
    __shared__ __align__(16) unsigned short A[4][48*AR];
    const int tid = threadIdx.x, w = tid >> 6, lane = tid & 63;
    const int g = lane >> 4, x = lane & 15;
    const int ch0 = w*16 + x;
    short8 B0[4], B1[4];
    #pragma unroll
    for (int ks = 0; ks < 4; ++ks) {
        B0[ks] = *(const short8*)(Wpk + ((w*4 + ks)*64 + lane)*8);
        B1[ks] = *(const short8*)(Wpk + (((w+4)*4 + ks)*64 + lane)*8);
    }
    for (int idx = tid; idx < 4*48*AR/2; idx += 256) ((unsigned int*)A)[idx] = 0u;

    uint2 st0[6], st1[6];
    int rN0[6] = {0,0,0,0,0,0}, rN1[6] = {0,0,0,0,0,0};
    int rM0[6] = {0,0,0,0,0,0}, rM1[6] = {0,0,0,0,0,0};
    float s0 = 0.f, q0 = 0.f, s1 = 0.f, q1 = 0.f;

#define LOAD_NBR(GRP, R)                                                      \
    {   const int base_ = (GRP)*4;                                            \
        _Pragma("unroll")                                                     \
        for (int it = 0; it < 6; ++it) {                                      \
            int idx = it*256 + tid;                                           \
            int p = idx >> 5, c = idx & 31;                                   \
            if (c < 16) R[it] = nbr[base_*MNBR + p];                          \
        } }

#define GATHER(GRP, R, ST)                                                    \
    {   const int base_ = (GRP)*4;                                            \
        _Pragma("unroll")                                                     \
        for (int it = 0; it < 6; ++it) {                                      \
            int idx = it*256 + tid;                                           \
            int p = idx >> 5, c = idx & 31;                                   \
            if (c < 16) {                                                     \
                ST[it] = *(const uint2*)(atomBf + ((size_t)R[it] << 6) + 4*c);\
            } else if (c < 27) {                                              \
                int cc = c - 16;                                              \
                int pa = p/12;                                                \
                const float* bp = bond + (size_t)(base_ + pa)*(MNBR*BDIM)     \
                                       + (p - pa*12)*BDIM + 4*cc;             \
                float b0 = bp[0], b1 = 0.f, b2 = 0.f, b3 = 0.f;               \
                if (cc < 10) { b1 = bp[1]; b2 = bp[2]; b3 = bp[3]; }          \
                ST[it].x = pkbf(b0, b1); ST[it].y = pkbf(b2, b3);             \
            }                                                                 \
        } }

#define WRITEA(BUF, ST)                                                       \
    {   _Pragma("unroll")                                                     \
        for (int it = 0; it < 6; ++it) {                                      \
            int idx = it*256 + tid;                                           \
            int p = idx >> 5, c = idx & 31;                                   \
            if (c < 16)      *(uint2*)(&A[BUF][p*AR + 4*c]) = ST[it];         \
            else if (c < 27) *(uint2*)(&A[BUF][p*AR + 64 + 4*(c-16)]) = ST[it]; \
        } }

#define COMPUTE(GRP, BUF)                                                     \
    {   const int base = (GRP)*4;                                             \
        f32x4 z = {0.f, 0.f, 0.f, 0.f};                                       \
        f32x4 acc[3][2];                                                      \
        _Pragma("unroll")                                                     \
        for (int m = 0; m < 3; ++m) { acc[m][0] = z; acc[m][1] = z; }         \
        _Pragma("unroll")                                                     \
        for (int ks = 0; ks < 4; ++ks) {                                      \
            _Pragma("unroll")                                                 \
            for (int m = 0; m < 3; ++m) {                                     \
                short8 a = *(const short8*)(&A[BUF][(m*16 + x)*AR + ks*32 + g*8]); \
                acc[m][0] = __builtin_amdgcn_mfma_f32_16x16x32_bf16(a, B0[ks], acc[m][0], 0, 0, 0); \
                acc[m][1] = __builtin_amdgcn_mfma_f32_16x16x32_bf16(a, B1[ks], acc[m][1], 0, 0, 0); \
            }                                                                 \
        }                                                                     \
        uint4* gbase = gated + ((size_t)(GRP)*4 + w)*3*64 + lane;             \
        _Pragma("unroll")                                                     \
        for (int m = 0; m < 3; ++m) {                                         \
            int ia = base + (m*16 + g*4)/12;                                  \
            float ps0 = bf2f(PselfBf[(size_t)ia*C2F + ch0]);                  \
            float ps1 = bf2f(PselfBf[(size_t)ia*C2F + 64 + ch0]);             \
            float v00 = acc[m][0][0] + ps0, v01 = acc[m][0][1] + ps0;         \
            float v02 = acc[m][0][2] + ps0, v03 = acc[m][0][3] + ps0;         \
            float v10 = acc[m][1][0] + ps1, v11 = acc[m][1][1] + ps1;         \
            float v12 = acc[m][1][2] + ps1, v13 = acc[m][1][3] + ps1;         \
            s0 += (v00 + v01) + (v02 + v03);                                  \
            s1 += (v10 + v11) + (v12 + v13);                                  \
            q0 = fmaf(v00, v00, q0); q0 = fmaf(v01, v01, q0);                 \
            q0 = fmaf(v02, v02, q0); q0 = fmaf(v03, v03, q0);                 \
            q1 = fmaf(v10, v10, q1); q1 = fmaf(v11, v11, q1);                 \
            q1 = fmaf(v12, v12, q1); q1 = fmaf(v13, v13, q1);                 \
            uint4 pk;                                                         \
            pk.x = pkbf(v00, v01); pk.y = pkbf(v02, v03);                     \
            pk.z = pkbf(v10, v11); pk.w = pkbf(v12, v13);                     \
            gbase[m*64] = pk;                                                 \
        } }

    const int S = gridDim.x;
    int grp = blockIdx.x;
    int cur = 0;
    // prologue: stage first pair of groups, then preload indices for the next pair
    if (grp < GROUPS)     { LOAD_NBR(grp,     rN0); GATHER(grp,     rN0, st0); WRITEA(0, st0); }
    if (grp + S < GROUPS) { LOAD_NBR(grp + S, rN1); GATHER(grp + S, rN1, st1); WRITEA(1, st1); }
    if (grp + 2*S < GROUPS) LOAD_NBR(grp + 2*S, rN0);
    if (grp + 3*S < GROUPS) LOAD_NBR(grp + 3*S, rN1);

    for (; grp + S < GROUPS; grp += 2*S) {
        const int n0 = grp + 2*S, n1 = grp + 3*S;
        __syncthreads();                          // A[cur..cur+1] staged; prior reads done
        if (n0 < GROUPS) GATHER(n0, rN0, st0);    // zero-wait: indices resident
        if (n1 < GROUPS) GATHER(n1, rN1, st1);
        if (n0 + 2*S < GROUPS) LOAD_NBR(n0 + 2*S, rM0);
        if (n1 + 2*S < GROUPS) LOAD_NBR(n1 + 2*S, rM1);
        COMPUTE(grp,     cur);
        COMPUTE(grp + S, cur + 1);
        if (n0 < GROUPS) WRITEA(cur ^ 2,       st0);   // st arrived under 48 MFMA
        if (n1 < GROUPS) WRITEA((cur ^ 2) + 1, st1);
        #pragma unroll
        for (int it = 0; it < 6; ++it) { rN0[it] = rM0[it]; rN1[it] = rM1[it]; }
        cur ^= 2;
    }
    if (grp < GROUPS) {                           // odd tail (staged as n0 last epoch)
        __syncthreads();
        COMPUTE(grp, cur);
    }
#undef LOAD_NBR
#undef GATHER
#undef WRITEA
#undef COMPUTE
    s0 += __shfl_xor(s0, 16); s0 += __shfl_xor(s0, 32);
    s1 += __shfl_xor(s1, 16); s1 += __shfl_xor(s1, 32);
    q0 += __shfl_xor(q0, 16); q0 += __shfl_xor(q0, 32);
    q1 += __shfl_xor(q1, 16); q1 += __shfl_xor(q1, 32);
    if (g == 0) {
        float* pb = partial1 + blockIdx.x*256;     // {sum[128], sumsq[128]}
        pb[ch0]            = s0; pb[64 + ch0]        = s1;
        pb[C2F + ch0]      = q0; pb[C2F + 64 + ch0]  = q1;
    }
}

// ---------------- kernel: partial reduce 2048 -> 128 slots ----------------
__global__ __launch_bounds__(256) void k_red(
    const float* __restrict__ in, float* __restrict__ outp, int width)
{
    const int b = blockIdx.x;
    for (int c = threadIdx.x; c < width; c += 256) {
        float s = 0.f;
        #pragma unroll 4
        for (int k = 0; k < 16; ++k) s += in[(size_t)(b*16 + k)*width + c];
        outp[(size_t)b*width + c] = s;
    }
}

// ---------------- kernel 3: finalize BN1 params ----------------
__global__ __launch_bounds__(1024) void k_bn1_finalize(
    const float* __restrict__ red1, const float* __restrict__ scale,
    const float* __restrict__ offset, float* __restrict__ prm1)
{
    __shared__ float redS[1024], redQ[1024];
    const int tid = threadIdx.x, c = tid & 127, h = tid >> 7;   // 8 slices
    float S = 0.f, Q = 0.f;
    for (int blk = h; blk < 128; blk += 8) {
        S += red1[blk*256 + c];
        Q += red1[blk*256 + 128 + c];
    }
    redS[tid] = S; redQ[tid] = Q;
    __syncthreads();
    if (tid < 128) {
        float Sa = 0.f, Qa = 0.f;
        #pragma unroll
        for (int hh = 0; hh < 8; ++hh) { Sa += redS[hh*128 + c]; Qa += redQ[hh*128 + c]; }
        const float invn = 1.f / (float)(NATOMS * MNBR);
        float mean = Sa * invn;
        float var  = Qa * invn - mean*mean;
        float inv  = scale[c] * rsqrtf(var + EPSBN);
        prm1[c]       = inv;
        prm1[128 + c] = offset[c] - mean*inv;       // folded offset
    }
}

// ---------------- kernel 4: apply pass (stream gated, gate, nbr-sum) ----------------
__global__ __launch_bounds__(256, 8) void k_apply(
    const uint4* __restrict__ gated, const float* __restrict__ prm1,
    float* __restrict__ summed, float* __restrict__ partial2)
{
    __shared__ float Y[12*66];
    __shared__ float red[256];
    const int tid = threadIdx.x, w = tid >> 6, lane = tid & 63;
    const int g = lane >> 4, x = lane & 15;
    const int ch0 = w*16 + x;
    const float iv0 = prm1[ch0],      of0 = prm1[C2F + ch0];
    const float iv1 = prm1[64 + ch0], of1 = prm1[C2F + 64 + ch0];
    float s2 = 0.f, q2 = 0.f;

    for (int grp = blockIdx.x; grp < GROUPS; grp += gridDim.x) {
        __syncthreads();
        const uint4* gbase = gated + ((size_t)grp*4 + w)*3*64 + lane;
        #pragma unroll
        for (int m = 0; m < 3; ++m) {
            uint4 pk = gbase[m*64];
            float y00 = bflo(pk.x)*iv0 + of0, y01 = bfhi(pk.x)*iv0 + of0;
            float y02 = bflo(pk.y)*iv0 + of0, y03 = bfhi(pk.y)*iv0 + of0;
            float y10 = bflo(pk.z)*iv1 + of1, y11 = bfhi(pk.z)*iv1 + of1;
            float y12 = bflo(pk.w)*iv1 + of1, y13 = bfhi(pk.w)*iv1 + of1;
            float sY = sigmoidf(y00)*softplusf(y10) + sigmoidf(y01)*softplusf(y11)
                     + sigmoidf(y02)*softplusf(y12) + sigmoidf(y03)*softplusf(y13);
            Y[(m*4 + g)*66 + ch0] = sY;
        }
        __syncthreads();
        float sv = Y[(3*w)*66 + lane] + Y[(3*w + 1)*66 + lane] + Y[(3*w + 2)*66 + lane];
        summed[(size_t)(grp*4 + w)*FDIM + lane] = sv;
        s2 += sv; q2 = fmaf(sv, sv, q2);
    }
    red[tid] = s2; __syncthreads();
    if (tid < 64) partial2[blockIdx.x*128 + tid]
        = red[tid] + red[tid+64] + red[tid+128] + red[tid+192];
    __syncthreads();
    red[tid] = q2; __syncthreads();
    if (tid < 64) partial2[blockIdx.x*128 + 64 + tid]
        = red[tid] + red[tid+64] + red[tid+128] + red[tid+192];
}

// ---------------- kernel 5: finalize BN2 params ----------------
__global__ __launch_bounds__(1024) void k_bn2_finalize(
    const float* __restrict__ red2, const float* __restrict__ scale,
    const float* __restrict__ offset, float* __restrict__ prm2)
{
    __shared__ float redS[1024], redQ[1024];
    const int tid = threadIdx.x, f = tid & 63, h = tid >> 6;    // 16 slices
    float S = 0.f, Q = 0.f;
    for (int blk = h; blk < 128; blk += 16) {
        S += red2[blk*128 + f];
        Q += red2[blk*128 + 64 + f];
    }
    redS[tid] = S; redQ[tid] = Q;
    __syncthreads();
    if (tid < 64) {
        float Sa = 0.f, Qa = 0.f;
        #pragma unroll
        for (int hh = 0; hh < 16; ++hh) { Sa += redS[hh*64 + f]; Qa += redQ[hh*64 + f]; }
        const float invn = 1.f / (float)NATOMS;
        float mean = Sa * invn;
        float var  = Qa * invn - mean*mean;
        float inv  = scale[f] * rsqrtf(var + EPSBN);
        prm2[f]      = inv;
        prm2[64 + f] = offset[f] - mean*inv;
    }
}

// ---------------- kernel 6: residual + softplus ----------------
__global__ __launch_bounds__(256) void k_final(
    const float* __restrict__ atomF, const float* __restrict__ summed,
    const float* __restrict__ prm2, float* __restrict__ out)
{
    __shared__ float iv[64], of[64];
    if (threadIdx.x < 64) {
        iv[threadIdx.x] = prm2[threadIdx.x];
        of[threadIdx.x] = prm2[64 + threadIdx.x];
    }
    __syncthreads();
    const int total4 = NATOMS*FDIM/4;
    for (int t = blockIdx.x*blockDim.x + threadIdx.x; t < total4;
         t += gridDim.x*blockDim.x) {
        float4 a = ((const float4*)atomF)[t];
        float4 s = ((const float4*)summed)[t];
        int fb = (t*4) & 63;
        float4 r;
        r.x = softplusf(a.x + s.x*iv[fb]   + of[fb]);
        r.y = softplusf(a.y + s.y*iv[fb+1] + of[fb+1]);
        r.z = softplusf(a.z + s.z*iv[fb+2] + of[fb+2]);
        r.w = softplusf(a.w + s.w*iv[fb+3] + of[fb+3]);
        ((float4*)out)[t] = r;
    }
}

extern "C" void kernel_launch(void* const* d_in, const int* in_sizes, int n_in,
                              void* d_out, int out_size, void* d_ws, size_t ws_size,
                              hipStream_t stream)
{
    const int*   nbr   = (const int*)  d_in[0];
    const float* atomF = (const float*)d_in[1];
    const float* bond  = (const float*)d_in[2];
    const float* W     = (const float*)d_in[3];
    // d_in[4] = b: cancels through BN1 (shift invariance) -> unused
    const float* s1    = (const float*)d_in[5];
    const float* o1    = (const float*)d_in[6];
    const float* s2    = (const float*)d_in[7];
    const float* o2    = (const float*)d_in[8];
    float* out = (float*)d_out;

    // ws layout (~375 MB total)
    uint4* gated        = (uint4*)d_ws;                          // GROUPS*12*64*16B = 307.2MB
    unsigned short* PselfBf = (unsigned short*)(gated + (size_t)GROUPS*12*64);  // N*128 bf16
    unsigned short* atomBf  = PselfBf + (size_t)NATOMS*C2F;      // N*64 bf16
    float* summed   = (float*)(atomBf + (size_t)NATOMS*FDIM);    // N*64 f32
    float* partial1 = summed   + (size_t)NATOMS*FDIM;            // 2048*256
    float* partial2 = partial1 + (size_t)NBLK*256;               // 2048*128
    float* red1     = partial2 + (size_t)NBLK*128;               // 128*256
    float* red2     = red1     + 128*256;                        // 128*128
    float* prm1     = red2     + 128*128;                        // 256
    float* prm2     = prm1     + 256;                            // 128
    unsigned short* Wsn = (unsigned short*)(prm2 + 128);         // 8192 shorts
    unsigned short* Wpk = Wsn + 8192;                            // 16384 shorts

    hipLaunchKernelGGL(k_pack,         dim3(64),   dim3(256),  0, stream, W, Wsn, Wpk);
    hipLaunchKernelGGL(k_proj,         dim3(782),  dim3(256),  0, stream,
                       atomF, Wsn, PselfBf, atomBf);
    hipLaunchKernelGGL(k_gemm,         dim3(NBLK), dim3(256),  0, stream,
                       nbr, atomBf, bond, Wpk, PselfBf, gated, partial1);
    hipLaunchKernelGGL(k_red,          dim3(128),  dim3(256),  0, stream, partial1, red1, 256);
    hipLaunchKernelGGL(k_bn1_finalize, dim3(1),    dim3(1024), 0, stream, red1, s1, o1, prm1);
    hipLaunchKernelGGL(k_apply,        dim3(NBLK), dim3(256),  0, stream,
                       gated, prm1, summed, partial2);
    hipLaunchKernelGGL(k_red,          dim3(128),  dim3(256),  0, stream, partial2, red2, 128);
    hipLaunchKernelGGL(k_bn2_finalize, dim3(1),    dim3(1024), 0, stream, red2, s2, o2, prm2);
    hipLaunchKernelGGL(k_final,        dim3(2048), dim3(256),  0, stream, atomF, summed, prm2, out);
}

// Round 16
// 373.356 us; speedup vs baseline: 2.2201x; 1.5497x over previous
//
#include <hip/hip_runtime.h>
#include <hip/hip_bf16.h>
#include <math.h>

// CGConv: N=100000 atoms, M=12 nbrs, F=64 atom-feat, B=41 bond-feat
// gated = [self | nbr | bond] @ W + b ; BN1 over N*M rows ;
// summed = sum_j sigmoid(filter)*softplus(core) ; BN2 over N rows ;
// out = softplus(atom + summed_bn)
//
// R16 = R11 (best, 372us) + SOFT BARRIER in k_gemm's loop.
// __syncthreads drains vmcnt(0) -> flushes the in-flight GATHER(t+1) and
// LOAD_NBR(t+2) pipeline every group (the m97 barrier-drain stall). This
// explains R11's modest gain and R13's failure (more waves, same drain).
// Soft barrier = s_waitcnt lgkmcnt(0) (covers ds_write/ds_read of the
// double-buffered A across waves) + raw s_barrier; vmcnt stays COUNTED --
// compiler still inserts vmcnt(N) before each register use (G7), so
// global loads stay in flight across the barrier (T4).
// R13/R14/R15 all regressed (occupancy / no-barrier / 2-group epoch spill)
// -> R11 structure is otherwise frozen. Spill watch: VGPR!=64 or
// WRITE_SIZE >> 320MB -> revert.
// BN1 two-pass forced (sumsq cross-term per-pair); bias b cancels in BN1.

#define NATOMS  100000
#define MNBR    12
#define FDIM    64
#define BDIM    41
#define C2F     128
#define EPSBN   1e-5f
#define NBLK    2048              // pair-kernel grid (= #partial slots)
#define GROUPS  (NATOMS/4)        // 25000 groups of 4 atoms = 48 pairs
#define AR      136               // pair A-tile row stride (shorts)
#define PR      72                // proj A-tile row stride (shorts)

typedef __attribute__((ext_vector_type(8))) short  short8;   // bf16 x8 frag
typedef __attribute__((ext_vector_type(4))) float  f32x4;    // C/D frag

__device__ __forceinline__ float softplusf(float x) {
    return fmaxf(x, 0.f) + __logf(1.f + __expf(-fabsf(x)));
}
__device__ __forceinline__ float sigmoidf(float x) {
    return 1.f / (1.f + __expf(-x));
}
__device__ __forceinline__ unsigned short f2bf(float f) {
    unsigned int x = __builtin_bit_cast(unsigned int, f);
    unsigned int r = (x + 0x7fff + ((x >> 16) & 1)) >> 16;  // RNE
    return (unsigned short)r;
}
__device__ __forceinline__ unsigned int pkbf(float a, float b) {
    unsigned short lo = __builtin_bit_cast(unsigned short, __float2bfloat16(a));
    unsigned short hi = __builtin_bit_cast(unsigned short, __float2bfloat16(b));
    return (unsigned)lo | ((unsigned)hi << 16);
}
__device__ __forceinline__ float bflo(unsigned int u) {
    return __builtin_bit_cast(float, u << 16);
}
__device__ __forceinline__ float bfhi(unsigned int u) {
    return __builtin_bit_cast(float, u & 0xffff0000u);
}
__device__ __forceinline__ float bf2f(unsigned short u) {
    return __builtin_bit_cast(float, ((unsigned int)u) << 16);
}
// Soft barrier: ds-op completion only (lgkmcnt), vmcnt stays counted so
// global loads/stores remain in flight across the barrier (T4).
__device__ __forceinline__ void softbar() {
    asm volatile("s_waitcnt lgkmcnt(0)" ::: "memory");
    __builtin_amdgcn_s_barrier();
    asm volatile("" ::: "memory");
}

// ---------------- kernel 0: prepack W fragments ----------------
// Wsn: self rows,  [n<8][ks<2][lane][e], k = ks*32+(lane>>4)*8+e, col=n*16+(lane&15)
// Wpk: nbr+bond rows, [n<8][ks<4][lane][e]; k<105 -> W[64+k][col] else 0
__global__ __launch_bounds__(256) void k_pack(
    const float* __restrict__ W,
    unsigned short* __restrict__ Wsn, unsigned short* __restrict__ Wpk)
{
    const int t0 = blockIdx.x*256 + threadIdx.x;
    for (int idx = t0; idx < 8*2*64*8; idx += gridDim.x*256) {
        int e = idx & 7, lane = (idx >> 3) & 63, ks = (idx >> 9) & 1, n = idx >> 10;
        int k   = ks*32 + (lane >> 4)*8 + e;
        int col = n*16 + (lane & 15);
        Wsn[idx] = f2bf(W[k*C2F + col]);
    }
    for (int idx = t0; idx < 8*4*64*8; idx += gridDim.x*256) {
        int e = idx & 7, lane = (idx >> 3) & 63, ks = (idx >> 9) & 3, n = idx >> 11;
        int k   = ks*32 + (lane >> 4)*8 + e;
        int col = n*16 + (lane & 15);
        float v = (k < 105) ? W[(64 + k)*C2F + col] : 0.f;
        Wpk[idx] = f2bf(v);
    }
}

// ---------------- kernel 1: Pself (MFMA) + atomBf pack ----------------
__global__ __launch_bounds__(256, 4) void k_proj(
    const float* __restrict__ atomF, const unsigned short* __restrict__ Wsn,
    unsigned short* __restrict__ PselfBf, unsigned short* __restrict__ atomBf)
{
    __shared__ __align__(16) unsigned short A[64*PR];
    const int tid = threadIdx.x, w = tid >> 6, lane = tid & 63;
    const int g = lane >> 4, x = lane & 15;
    short8 B0[2], B1[2];
    #pragma unroll
    for (int ks = 0; ks < 2; ++ks) {
        B0[ks] = *(const short8*)(Wsn + ((w*2 + ks)*64 + lane)*8);
        B1[ks] = *(const short8*)(Wsn + (((w+4)*2 + ks)*64 + lane)*8);
    }
    for (int a0 = blockIdx.x*64; a0 < NATOMS; a0 += gridDim.x*64) {
        __syncthreads();
        #pragma unroll
        for (int it = 0; it < 4; ++it) {
            int idx = it*256 + tid;
            int p = idx >> 4, c = idx & 15;
            int i = a0 + p;
            float4 v = make_float4(0.f, 0.f, 0.f, 0.f);
            if (i < NATOMS) v = *(const float4*)(atomF + (size_t)i*FDIM + 4*c);
            uint2 u; u.x = pkbf(v.x, v.y); u.y = pkbf(v.z, v.w);
            *(uint2*)(A + p*PR + 4*c) = u;
            if (i < NATOMS) *(uint2*)(atomBf + (size_t)i*FDIM + 4*c) = u;
        }
        __syncthreads();
        f32x4 z = {0.f, 0.f, 0.f, 0.f};
        f32x4 acc[4][2];
        #pragma unroll
        for (int m = 0; m < 4; ++m) { acc[m][0] = z; acc[m][1] = z; }
        #pragma unroll
        for (int ks = 0; ks < 2; ++ks) {
            #pragma unroll
            for (int m = 0; m < 4; ++m) {
                short8 a = *(const short8*)(A + (m*16 + x)*PR + ks*32 + g*8);
                acc[m][0] = __builtin_amdgcn_mfma_f32_16x16x32_bf16(a, B0[ks], acc[m][0], 0, 0, 0);
                acc[m][1] = __builtin_amdgcn_mfma_f32_16x16x32_bf16(a, B1[ks], acc[m][1], 0, 0, 0);
            }
        }
        #pragma unroll
        for (int m = 0; m < 4; ++m) {
            int i = a0 + m*16 + g*4;
            #pragma unroll
            for (int rg = 0; rg < 4; ++rg) {
                if (i + rg < NATOMS) {
                    PselfBf[(size_t)(i+rg)*C2F + w*16 + x]     = f2bf(acc[m][0][rg]);
                    PselfBf[(size_t)(i+rg)*C2F + (w+4)*16 + x] = f2bf(acc[m][1][rg]);
                }
            }
        }
    }
}

// ---------------- kernel 2: pair GEMM + BN1 stats + gated store ----------------
// A rows = [nbr(64) | bond(41) | pad] bf16, K=128 (4 ksteps), M=48 pairs.
// 2-deep index pipeline (rN/rM) + double-buffered LDS + SOFT barriers.
// Slot map: idx=it*256+tid, p=idx>>5 (pair), c=idx&31; c<16: nbr quad;
// 16<=c<27: bond quad. gated: uint4 idx = ((grp*4+w)*3+m)*64+lane.
__global__ __launch_bounds__(256, 4) void k_gemm(
    const int* __restrict__ nbr, const unsigned short* __restrict__ atomBf,
    const float* __restrict__ bond, const unsigned short* __restrict__ Wpk,
    const unsigned short* __restrict__ PselfBf,
    uint4* __restrict__ gated, float* __restrict__ partial1)
{
    __shared__ __align__(16) unsigned short A[2][48*AR];
    const int tid = threadIdx.x, w = tid >> 6, lane = tid & 63;
    const int g = lane >> 4, x = lane & 15;
    const int ch0 = w*16 + x;
    short8 B0[4], B1[4];
    #pragma unroll
    for (int ks = 0; ks < 4; ++ks) {
        B0[ks] = *(const short8*)(Wpk + ((w*4 + ks)*64 + lane)*8);
        B1[ks] = *(const short8*)(Wpk + (((w+4)*4 + ks)*64 + lane)*8);
    }
    for (int idx = tid; idx < 2*48*AR/2; idx += 256) ((unsigned int*)A)[idx] = 0u;

    uint2 st[6];
    int rN[6] = {0,0,0,0,0,0};
    int rM[6] = {0,0,0,0,0,0};
    float s0 = 0.f, q0 = 0.f, s1 = 0.f, q1 = 0.f;

#define LOAD_NBR(GRP, R)                                                      \
    {   const int base_ = (GRP)*4;                                            \
        _Pragma("unroll")                                                     \
        for (int it = 0; it < 6; ++it) {                                      \
            int idx = it*256 + tid;                                           \
            int p = idx >> 5, c = idx & 31;                                   \
            if (c < 16) R[it] = nbr[base_*MNBR + p];                          \
        } }

#define GATHER(GRP, R)                                                        \
    {   const int base_ = (GRP)*4;                                            \
        _Pragma("unroll")                                                     \
        for (int it = 0; it < 6; ++it) {                                      \
            int idx = it*256 + tid;                                           \
            int p = idx >> 5, c = idx & 31;                                   \
            if (c < 16) {                                                     \
                st[it] = *(const uint2*)(atomBf + ((size_t)R[it] << 6) + 4*c);\
            } else if (c < 27) {                                              \
                int cc = c - 16;                                              \
                int pa = p/12;                                                \
                const float* bp = bond + (size_t)(base_ + pa)*(MNBR*BDIM)     \
                                       + (p - pa*12)*BDIM + 4*cc;             \
                float b0 = bp[0], b1 = 0.f, b2 = 0.f, b3 = 0.f;               \
                if (cc < 10) { b1 = bp[1]; b2 = bp[2]; b3 = bp[3]; }          \
                st[it].x = pkbf(b0, b1); st[it].y = pkbf(b2, b3);             \
            }                                                                 \
        } }

#define WRITEA(BUF)                                                           \
    {   _Pragma("unroll")                                                     \
        for (int it = 0; it < 6; ++it) {                                      \
            int idx = it*256 + tid;                                           \
            int p = idx >> 5, c = idx & 31;                                   \
            if (c < 16)      *(uint2*)(&A[BUF][p*AR + 4*c]) = st[it];         \
            else if (c < 27) *(uint2*)(&A[BUF][p*AR + 64 + 4*(c-16)]) = st[it]; \
        } }

    const int S = gridDim.x;
    int grp = blockIdx.x;
    int cur = 0;
    if (grp < GROUPS) {
        LOAD_NBR(grp, rN);                        // indices for grp
        GATHER(grp, rN);                          // stage grp
        WRITEA(0);
        if (grp + S < GROUPS) LOAD_NBR(grp + S, rN);  // rN -> indices for grp+S
    }
    for (; grp < GROUPS; grp += S) {
        const int nxt = grp + S;
        softbar();                                // lgkm only; vmcnt stays counted
        if (nxt < GROUPS) GATHER(nxt, rN);        // zero-wait: rN already resident
        if (nxt + S < GROUPS) LOAD_NBR(nxt + S, rM);  // indices for t+2
        f32x4 z = {0.f, 0.f, 0.f, 0.f};
        f32x4 acc[3][2];
        #pragma unroll
        for (int m = 0; m < 3; ++m) { acc[m][0] = z; acc[m][1] = z; }
        #pragma unroll
        for (int ks = 0; ks < 4; ++ks) {
            #pragma unroll
            for (int m = 0; m < 3; ++m) {
                short8 a = *(const short8*)(&A[cur][(m*16 + x)*AR + ks*32 + g*8]);
                acc[m][0] = __builtin_amdgcn_mfma_f32_16x16x32_bf16(a, B0[ks], acc[m][0], 0, 0, 0);
                acc[m][1] = __builtin_amdgcn_mfma_f32_16x16x32_bf16(a, B1[ks], acc[m][1], 0, 0, 0);
            }
        }
        const int base = grp*4;
        uint4* gbase = gated + ((size_t)grp*4 + w)*3*64 + lane;
        #pragma unroll
        for (int m = 0; m < 3; ++m) {
            int ia = base + (m*16 + g*4)/12;      // uniform over rg (proven)
            float ps0 = bf2f(PselfBf[(size_t)ia*C2F + ch0]);
            float ps1 = bf2f(PselfBf[(size_t)ia*C2F + 64 + ch0]);
            float v00 = acc[m][0][0] + ps0, v01 = acc[m][0][1] + ps0;
            float v02 = acc[m][0][2] + ps0, v03 = acc[m][0][3] + ps0;
            float v10 = acc[m][1][0] + ps1, v11 = acc[m][1][1] + ps1;
            float v12 = acc[m][1][2] + ps1, v13 = acc[m][1][3] + ps1;
            s0 += (v00 + v01) + (v02 + v03);
            s1 += (v10 + v11) + (v12 + v13);
            q0 = fmaf(v00, v00, q0); q0 = fmaf(v01, v01, q0);
            q0 = fmaf(v02, v02, q0); q0 = fmaf(v03, v03, q0);
            q1 = fmaf(v10, v10, q1); q1 = fmaf(v11, v11, q1);
            q1 = fmaf(v12, v12, q1); q1 = fmaf(v13, v13, q1);
            uint4 pk;
            pk.x = pkbf(v00, v01); pk.y = pkbf(v02, v03);
            pk.z = pkbf(v10, v11); pk.w = pkbf(v12, v13);
            gbase[m*64] = pk;
        }
        if (nxt < GROUPS) WRITEA(cur ^ 1);        // st arrived under MFMA+epilogue
        #pragma unroll
        for (int it = 0; it < 6; ++it) rN[it] = rM[it];
        cur ^= 1;
    }
#undef LOAD_NBR
#undef GATHER
#undef WRITEA
    s0 += __shfl_xor(s0, 16); s0 += __shfl_xor(s0, 32);
    s1 += __shfl_xor(s1, 16); s1 += __shfl_xor(s1, 32);
    q0 += __shfl_xor(q0, 16); q0 += __shfl_xor(q0, 32);
    q1 += __shfl_xor(q1, 16); q1 += __shfl_xor(q1, 32);
    if (g == 0) {
        float* pb = partial1 + blockIdx.x*256;     // {sum[128], sumsq[128]}
        pb[ch0]            = s0; pb[64 + ch0]        = s1;
        pb[C2F + ch0]      = q0; pb[C2F + 64 + ch0]  = q1;
    }
}

// ---------------- kernel: partial reduce 2048 -> 128 slots ----------------
__global__ __launch_bounds__(256) void k_red(
    const float* __restrict__ in, float* __restrict__ outp, int width)
{
    const int b = blockIdx.x;
    for (int c = threadIdx.x; c < width; c += 256) {
        float s = 0.f;
        #pragma unroll 4
        for (int k = 0; k < 16; ++k) s += in[(size_t)(b*16 + k)*width + c];
        outp[(size_t)b*width + c] = s;
    }
}

// ---------------- kernel 3: finalize BN1 params ----------------
__global__ __launch_bounds__(1024) void k_bn1_finalize(
    const float* __restrict__ red1, const float* __restrict__ scale,
    const float* __restrict__ offset, float* __restrict__ prm1)
{
    __shared__ float redS[1024], redQ[1024];
    const int tid = threadIdx.x, c = tid & 127, h = tid >> 7;   // 8 slices
    float S = 0.f, Q = 0.f;
    for (int blk = h; blk < 128; blk += 8) {
        S += red1[blk*256 + c];
        Q += red1[blk*256 + 128 + c];
    }
    redS[tid] = S; redQ[tid] = Q;
    __syncthreads();
    if (tid < 128) {
        float Sa = 0.f, Qa = 0.f;
        #pragma unroll
        for (int hh = 0; hh < 8; ++hh) { Sa += redS[hh*128 + c]; Qa += redQ[hh*128 + c]; }
        const float invn = 1.f / (float)(NATOMS * MNBR);
        float mean = Sa * invn;
        float var  = Qa * invn - mean*mean;
        float inv  = scale[c] * rsqrtf(var + EPSBN);
        prm1[c]       = inv;
        prm1[128 + c] = offset[c] - mean*inv;       // folded offset
    }
}

// ---------------- kernel 4: apply pass (stream gated, gate, nbr-sum) ----------------
__global__ __launch_bounds__(256, 8) void k_apply(
    const uint4* __restrict__ gated, const float* __restrict__ prm1,
    float* __restrict__ summed, float* __restrict__ partial2)
{
    __shared__ float Y[12*66];
    __shared__ float red[256];
    const int tid = threadIdx.x, w = tid >> 6, lane = tid & 63;
    const int g = lane >> 4, x = lane & 15;
    const int ch0 = w*16 + x;
    const float iv0 = prm1[ch0],      of0 = prm1[C2F + ch0];
    const float iv1 = prm1[64 + ch0], of1 = prm1[C2F + 64 + ch0];
    float s2 = 0.f, q2 = 0.f;

    for (int grp = blockIdx.x; grp < GROUPS; grp += gridDim.x) {
        __syncthreads();
        const uint4* gbase = gated + ((size_t)grp*4 + w)*3*64 + lane;
        #pragma unroll
        for (int m = 0; m < 3; ++m) {
            uint4 pk = gbase[m*64];
            float y00 = bflo(pk.x)*iv0 + of0, y01 = bfhi(pk.x)*iv0 + of0;
            float y02 = bflo(pk.y)*iv0 + of0, y03 = bfhi(pk.y)*iv0 + of0;
            float y10 = bflo(pk.z)*iv1 + of1, y11 = bfhi(pk.z)*iv1 + of1;
            float y12 = bflo(pk.w)*iv1 + of1, y13 = bfhi(pk.w)*iv1 + of1;
            float sY = sigmoidf(y00)*softplusf(y10) + sigmoidf(y01)*softplusf(y11)
                     + sigmoidf(y02)*softplusf(y12) + sigmoidf(y03)*softplusf(y13);
            Y[(m*4 + g)*66 + ch0] = sY;
        }
        __syncthreads();
        float sv = Y[(3*w)*66 + lane] + Y[(3*w + 1)*66 + lane] + Y[(3*w + 2)*66 + lane];
        summed[(size_t)(grp*4 + w)*FDIM + lane] = sv;
        s2 += sv; q2 = fmaf(sv, sv, q2);
    }
    red[tid] = s2; __syncthreads();
    if (tid < 64) partial2[blockIdx.x*128 + tid]
        = red[tid] + red[tid+64] + red[tid+128] + red[tid+192];
    __syncthreads();
    red[tid] = q2; __syncthreads();
    if (tid < 64) partial2[blockIdx.x*128 + 64 + tid]
        = red[tid] + red[tid+64] + red[tid+128] + red[tid+192];
}

// ---------------- kernel 5: finalize BN2 params ----------------
__global__ __launch_bounds__(1024) void k_bn2_finalize(
    const float* __restrict__ red2, const float* __restrict__ scale,
    const float* __restrict__ offset, float* __restrict__ prm2)
{
    __shared__ float redS[1024], redQ[1024];
    const int tid = threadIdx.x, f = tid & 63, h = tid >> 6;    // 16 slices
    float S = 0.f, Q = 0.f;
    for (int blk = h; blk < 128; blk += 16) {
        S += red2[blk*128 + f];
        Q += red2[blk*128 + 64 + f];
    }
    redS[tid] = S; redQ[tid] = Q;
    __syncthreads();
    if (tid < 64) {
        float Sa = 0.f, Qa = 0.f;
        #pragma unroll
        for (int hh = 0; hh < 16; ++hh) { Sa += redS[hh*64 + f]; Qa += redQ[hh*64 + f]; }
        const float invn = 1.f / (float)NATOMS;
        float mean = Sa * invn;
        float var  = Qa * invn - mean*mean;
        float inv  = scale[f] * rsqrtf(var + EPSBN);
        prm2[f]      = inv;
        prm2[64 + f] = offset[f] - mean*inv;
    }
}

// ---------------- kernel 6: residual + softplus ----------------
__global__ __launch_bounds__(256) void k_final(
    const float* __restrict__ atomF, const float* __restrict__ summed,
    const float* __restrict__ prm2, float* __restrict__ out)
{
    __shared__ float iv[64], of[64];
    if (threadIdx.x < 64) {
        iv[threadIdx.x] = prm2[threadIdx.x];
        of[threadIdx.x] = prm2[64 + threadIdx.x];
    }
    __syncthreads();
    const int total4 = NATOMS*FDIM/4;
    for (int t = blockIdx.x*blockDim.x + threadIdx.x; t < total4;
         t += gridDim.x*blockDim.x) {
        float4 a = ((const float4*)atomF)[t];
        float4 s = ((const float4*)summed)[t];
        int fb = (t*4) & 63;
        float4 r;
        r.x = softplusf(a.x + s.x*iv[fb]   + of[fb]);
        r.y = softplusf(a.y + s.y*iv[fb+1] + of[fb+1]);
        r.z = softplusf(a.z + s.z*iv[fb+2] + of[fb+2]);
        r.w = softplusf(a.w + s.w*iv[fb+3] + of[fb+3]);
        ((float4*)out)[t] = r;
    }
}

extern "C" void kernel_launch(void* const* d_in, const int* in_sizes, int n_in,
                              void* d_out, int out_size, void* d_ws, size_t ws_size,
                              hipStream_t stream)
{
    const int*   nbr   = (const int*)  d_in[0];
    const float* atomF = (const float*)d_in[1];
    const float* bond  = (const float*)d_in[2];
    const float* W     = (const float*)d_in[3];
    // d_in[4] = b: cancels through BN1 (shift invariance) -> unused
    const float* s1    = (const float*)d_in[5];
    const float* o1    = (const float*)d_in[6];
    const float* s2    = (const float*)d_in[7];
    const float* o2    = (const float*)d_in[8];
    float* out = (float*)d_out;

    // ws layout (~375 MB total)
    uint4* gated        = (uint4*)d_ws;                          // GROUPS*12*64*16B = 307.2MB
    unsigned short* PselfBf = (unsigned short*)(gated + (size_t)GROUPS*12*64);  // N*128 bf16
    unsigned short* atomBf  = PselfBf + (size_t)NATOMS*C2F;      // N*64 bf16
    float* summed   = (float*)(atomBf + (size_t)NATOMS*FDIM);    // N*64 f32
    float* partial1 = summed   + (size_t)NATOMS*FDIM;            // 2048*256
    float* partial2 = partial1 + (size_t)NBLK*256;               // 2048*128
    float* red1     = partial2 + (size_t)NBLK*128;               // 128*256
    float* red2     = red1     + 128*256;                        // 128*128
    float* prm1     = red2     + 128*128;                        // 256
    float* prm2     = prm1     + 256;                            // 128
    unsigned short* Wsn = (unsigned short*)(prm2 + 128);         // 8192 shorts
    unsigned short* Wpk = Wsn + 8192;                            // 16384 shorts

    hipLaunchKernelGGL(k_pack,         dim3(64),   dim3(256),  0, stream, W, Wsn, Wpk);
    hipLaunchKernelGGL(k_proj,         dim3(782),  dim3(256),  0, stream,
                       atomF, Wsn, PselfBf, atomBf);
    hipLaunchKernelGGL(k_gemm,         dim3(NBLK), dim3(256),  0, stream,
                       nbr, atomBf, bond, Wpk, PselfBf, gated, partial1);
    hipLaunchKernelGGL(k_red,          dim3(128),  dim3(256),  0, stream, partial1, red1, 256);
    hipLaunchKernelGGL(k_bn1_finalize, dim3(1),    dim3(1024), 0, stream, red1, s1, o1, prm1);
    hipLaunchKernelGGL(k_apply,        dim3(NBLK), dim3(256),  0, stream,
                       gated, prm1, summed, partial2);
    hipLaunchKernelGGL(k_red,          dim3(128),  dim3(256),  0, stream, partial2, red2, 128);
    hipLaunchKernelGGL(k_bn2_finalize, dim3(1),    dim3(1024), 0, stream, red2, s2, o2, prm2);
    hipLaunchKernelGGL(k_final,        dim3(2048), dim3(256),  0, stream, atomF, summed, prm2, out);
}